// Round 6
// baseline (602.828 us; speedup 1.0000x reference)
//
#include <hip/hip_runtime.h>

#define AS1 __attribute__((address_space(1)))
#define AS3 __attribute__((address_space(3)))

typedef __bf16 bf16x8 __attribute__((ext_vector_type(8)));
typedef float f32x4 __attribute__((ext_vector_type(4)));

__device__ __forceinline__ unsigned short f2bf(float f) {
  unsigned int u = __builtin_bit_cast(unsigned int, f);
  u += 0x7fffu + ((u >> 16) & 1u);   // round-to-nearest-even
  return (unsigned short)(u >> 16);
}

__device__ __forceinline__ void sink16(uint4& s, const void* p) {
  uint4 t; __builtin_memcpy(&t, p, 16);
  s.x ^= t.x; s.y ^= t.y; s.z ^= t.z; s.w ^= t.w;
}

// ---------------------------------------------------------------------------
// Transpose K/V (f32, [b,t,h*256+j]) -> bf16 tiles [pp][s][j:256][t:32]
// ---------------------------------------------------------------------------
__global__ __launch_bounds__(256) void kv_transpose(
    const float* __restrict__ key, const float* __restrict__ value,
    unsigned short* __restrict__ KT2, unsigned short* __restrict__ VT2) {
  __shared__ float tr[32 * 33];
  const int tid = threadIdx.x;
  const int ts  = blockIdx.y;          // 0 = K, 1 = V
  const int pp  = blockIdx.x >> 3;
  const int s   = blockIdx.x & 7;
  const int b   = ts ? (pp >> 4) : (pp & 15);
  const int h   = ts ? (pp & 15) : (pp >> 4);
  const float* src = (ts ? value : key) + ((size_t)(b * 256 + s * 32)) * 4096 + h * 256;
  unsigned short* dst = (ts ? VT2 : KT2) + (size_t)(pp * 8 + s) * 8192;
  const int tt = tid >> 3;   // 0..31
  const int q8 = tid & 7;    // 0..7
  for (int jb = 0; jb < 8; ++jb) {
    float4 v = *(const float4*)(src + (size_t)tt * 4096 + jb * 32 + q8 * 4);
    tr[tt * 33 + q8 * 4 + 0] = v.x;
    tr[tt * 33 + q8 * 4 + 1] = v.y;
    tr[tt * 33 + q8 * 4 + 2] = v.z;
    tr[tt * 33 + q8 * 4 + 3] = v.w;
    __syncthreads();
    ushort4 o;
    o.x = f2bf(tr[(q8 * 4 + 0) * 33 + tt]);
    o.y = f2bf(tr[(q8 * 4 + 1) * 33 + tt]);
    o.z = f2bf(tr[(q8 * 4 + 2) * 33 + tt]);
    o.w = f2bf(tr[(q8 * 4 + 3) * 33 + tt]);
    *(ushort4*)(dst + (jb * 32 + tt) * 32 + q8 * 4) = o;
    __syncthreads();
  }
}

// ---------------------------------------------------------------------------
// Attention (validated).
// ---------------------------------------------------------------------------
__global__ __launch_bounds__(256, 2) void attn_kernel(
    const float* __restrict__ qin, const unsigned short* __restrict__ KT2,
    const unsigned short* __restrict__ VT2, unsigned short* __restrict__ attn) {
  __shared__ __align__(16) unsigned short kv[8192];
  __shared__ __align__(16) unsigned short plds[4 * 16 * 264];

  const int tid  = threadIdx.x;
  const int lane = tid & 63;
  const int wave = tid >> 6;
  const int li   = lane & 15;
  const int ks   = lane >> 4;

  const int bid = blockIdx.x;
  const int pp  = (bid & 7) * 32 + ((bid >> 3) & 31);
  const int ib  = bid >> 8;
  const int x = pp >> 4, y = pp & 15;
  const int i0 = ib * 64 + wave * 16;

  bf16x8 qf[8];
  {
    const float* qrow = qin + ((size_t)(y * 256 + i0 + li)) * 4096 + x * 256 + ks * 8;
#pragma unroll
    for (int s = 0; s < 8; ++s) {
      float4 v0 = *(const float4*)(qrow + s * 32);
      float4 v1 = *(const float4*)(qrow + s * 32 + 4);
      union { bf16x8 v; unsigned short u[8]; } t;
      t.u[0] = f2bf(v0.x * 0.0625f); t.u[1] = f2bf(v0.y * 0.0625f);
      t.u[2] = f2bf(v0.z * 0.0625f); t.u[3] = f2bf(v0.w * 0.0625f);
      t.u[4] = f2bf(v1.x * 0.0625f); t.u[5] = f2bf(v1.y * 0.0625f);
      t.u[6] = f2bf(v1.z * 0.0625f); t.u[7] = f2bf(v1.w * 0.0625f);
      qf[s] = t.v;
    }
  }

  const f32x4 vzero = {0.f, 0.f, 0.f, 0.f};
  f32x4 sacc[16];
#pragma unroll
  for (int f = 0; f < 16; ++f) sacc[f] = vzero;

  const unsigned short* ktile = KT2 + (size_t)pp * 65536;
#pragma unroll
  for (int s = 0; s < 8; ++s) {
    __syncthreads();
#pragma unroll
    for (int cc = 0; cc < 4; ++cc) {
      const unsigned short* g = ktile + (size_t)s * 8192 + (cc * 256 + tid) * 8;
      __builtin_amdgcn_global_load_lds((AS1 unsigned int*)g,
          (AS3 unsigned int*)((AS3 char*)kv + cc * 4096 + wave * 1024), 16, 0, 0);
    }
    __syncthreads();
#pragma unroll
    for (int f = 0; f < 16; ++f) {
      bf16x8 bfr = *(const bf16x8*)&kv[(f * 16 + li) * 32 + ks * 8];
      sacc[f] = __builtin_amdgcn_mfma_f32_16x16x32_bf16(qf[s], bfr, sacc[f], 0, 0, 0);
    }
  }

  float sm[4];
#pragma unroll
  for (int qi = 0; qi < 4; ++qi) {
    float m = sacc[0][qi];
#pragma unroll
    for (int f = 1; f < 16; ++f) m = fmaxf(m, sacc[f][qi]);
    m = fmaxf(m, __shfl_xor(m, 1));
    m = fmaxf(m, __shfl_xor(m, 2));
    m = fmaxf(m, __shfl_xor(m, 4));
    m = fmaxf(m, __shfl_xor(m, 8));
    float ssum = 0.f;
#pragma unroll
    for (int f = 0; f < 16; ++f) {
      float pv = __expf(sacc[f][qi] - m);
      sacc[f][qi] = pv;
      ssum += pv;
    }
    ssum += __shfl_xor(ssum, 1);
    ssum += __shfl_xor(ssum, 2);
    ssum += __shfl_xor(ssum, 4);
    ssum += __shfl_xor(ssum, 8);
    sm[qi] = ssum;
  }

  unsigned short* pw = plds + wave * 4224;
#pragma unroll
  for (int f = 0; f < 16; ++f)
#pragma unroll
    for (int qi = 0; qi < 4; ++qi)
      pw[(ks * 4 + qi) * 264 + f * 16 + li] = f2bf(sacc[f][qi]);

  f32x4 oacc[16];
#pragma unroll
  for (int f = 0; f < 16; ++f) oacc[f] = vzero;
  const unsigned short* vtile = VT2 + (size_t)pp * 65536;
  const unsigned short* pr = plds + wave * 4224 + li * 264;
#pragma unroll
  for (int s2 = 0; s2 < 8; ++s2) {
    __syncthreads();
#pragma unroll
    for (int cc = 0; cc < 4; ++cc) {
      const unsigned short* g = vtile + (size_t)s2 * 8192 + (cc * 256 + tid) * 8;
      __builtin_amdgcn_global_load_lds((AS1 unsigned int*)g,
          (AS3 unsigned int*)((AS3 char*)kv + cc * 4096 + wave * 1024), 16, 0, 0);
    }
    __syncthreads();
    bf16x8 afr = *(const bf16x8*)&pr[s2 * 32 + ks * 8];
#pragma unroll
    for (int f = 0; f < 16; ++f) {
      bf16x8 bfr = *(const bf16x8*)&kv[(f * 16 + li) * 32 + ks * 8];
      oacc[f] = __builtin_amdgcn_mfma_f32_16x16x32_bf16(afr, bfr, oacc[f], 0, 0, 0);
    }
  }

  float rs4[4];
#pragma unroll
  for (int qi = 0; qi < 4; ++qi) rs4[qi] = 1.0f / sm[qi];
  unsigned short* abase = attn + (size_t)(x * 256 + i0 + ks * 4) * 4096 + y * 256 + li;
#pragma unroll
  for (int f = 0; f < 16; ++f)
#pragma unroll
    for (int qi = 0; qi < 4; ++qi)
      abase[(size_t)qi * 4096 + f * 16] = f2bf(oacc[f][qi] * rs4[qi]);
}

// ---------------------------------------------------------------------------
// out_w f32 -> bf16
// ---------------------------------------------------------------------------
__global__ __launch_bounds__(256) void convw(const float* __restrict__ w,
                                             unsigned short* __restrict__ o) {
  const int i = blockIdx.x * 256 + threadIdx.x;
  const float4* s = (const float4*)w + (size_t)i * 2;
  float4 v0 = s[0], v1 = s[1];
  uint4 pk;
  pk.x = (unsigned)f2bf(v0.x) | ((unsigned)f2bf(v0.y) << 16);
  pk.y = (unsigned)f2bf(v0.z) | ((unsigned)f2bf(v0.w) << 16);
  pk.z = (unsigned)f2bf(v1.x) | ((unsigned)f2bf(v1.y) << 16);
  pk.w = (unsigned)f2bf(v1.z) | ((unsigned)f2bf(v1.w) << 16);
  *((uint4*)o + i) = pk;
}

// ---------------------------------------------------------------------------
// R2 GEMM (best known: 132.6us, 0 bank conflicts) — the REAL output kernel.
// 256x256xBK=64, 8 waves (2M x 4N), 4 lockstep quadrant-phases/tile.
// ---------------------------------------------------------------------------
__global__ __launch_bounds__(512, 2) void proj_gemm8(
    const unsigned short* __restrict__ A, const unsigned short* __restrict__ W,
    const float* __restrict__ bias, float* __restrict__ out) {
  __shared__ __align__(1024) char lds[131072];

  const int tid  = threadIdx.x;
  const int lane = tid & 63;
  const int w    = tid >> 6;
  const int li   = lane & 15;
  const int ks   = lane >> 4;
  const int wr   = w >> 2;
  const int wc   = w & 3;
  const int LB   = (li * 64 + ks * 16) ^ (((li >> 3) & 1) << 5);

  const int bid = blockIdx.x;
  const int swz = (bid & 7) * 32 + (bid >> 3);
  const int m0b = (swz >> 4) * 256, n0b = (swz & 15) * 256;

  unsigned sA[2][2], sB[2][2];
#pragma unroll
  for (int i2 = 0; i2 < 2; ++i2) {
    int P = w * 2048 + i2 * 1024 + lane * 16;
    int L = P ^ (((P >> 9) & 1) << 5);
    int kk = L >> 13, row = (L >> 6) & 127, cb = L & 63;
#pragma unroll
    for (int h = 0; h < 2; ++h) {
      sA[h][i2] = (unsigned)((m0b + h * 128 + row) * 8192 + kk * 64 + cb);
      sB[h][i2] = (unsigned)((n0b + h * 128 + row) * 8192 + kk * 64 + cb);
    }
  }
  const char* Ac = (const char*)A;
  const char* Wc = (const char*)W;
  AS3 char* L3 = (AS3 char*)lds;

  const f32x4 vzero = {0.f, 0.f, 0.f, 0.f};
  f32x4 acc[8][4];
#pragma unroll
  for (int m = 0; m < 8; ++m)
#pragma unroll
    for (int n = 0; n < 4; ++n) acc[m][n] = vzero;

#define STAGE_A(h, i2, koffb, bufo) \
  __builtin_amdgcn_global_load_lds((AS1 unsigned int*)(Ac + sA[h][i2] + (koffb)), \
      (AS3 unsigned int*)(L3 + (bufo) + (h) * 16384 + w * 2048 + (i2) * 1024), 16, 0, 0)
#define STAGE_B(h, i2, koffb, bufo) \
  __builtin_amdgcn_global_load_lds((AS1 unsigned int*)(Wc + sB[h][i2] + (koffb)), \
      (AS3 unsigned int*)(L3 + 65536 + (bufo) + (h) * 16384 + w * 2048 + (i2) * 1024), 16, 0, 0)
#define RD_A(m, kk) (*(const bf16x8*)(lds + aoff + wr * 16384 + (kk) * 8192 + (m) * 1024 + LB))
#define RD_B(n, kk) (*(const bf16x8*)(lds + boff + (wc >> 1) * 16384 + (kk) * 8192 + \
                                      (wc & 1) * 4096 + (n) * 1024 + LB))
#define MFMA(a, b, c) __builtin_amdgcn_mfma_f32_16x16x32_bf16((a), (b), (c), 0, 0, 0)

#pragma unroll
  for (int tt = 0; tt < 2; ++tt) {
#pragma unroll
    for (int h = 0; h < 2; ++h)
#pragma unroll
      for (int i2 = 0; i2 < 2; ++i2) {
        STAGE_A(h, i2, tt * 128u, tt * 32768);
        STAGE_B(h, i2, tt * 128u, tt * 32768);
      }
  }
  asm volatile("s_waitcnt vmcnt(8)" ::: "memory");
  __builtin_amdgcn_s_barrier();

  bf16x8 afr[4][2], bA[2][2], bB[2][2];

  for (int t = 0; t < 64; ++t) {
    const int cur  = t & 1;
    const int aoff = cur * 32768;
    const int boff = 65536 + cur * 32768;
    const int ts   = (t + 2 < 64) ? t + 2 : 63;
    const unsigned koff = (unsigned)ts * 128u;

#pragma unroll
    for (int m = 0; m < 4; ++m)
#pragma unroll
      for (int kk = 0; kk < 2; ++kk) afr[m][kk] = RD_A(m, kk);
#pragma unroll
    for (int n = 0; n < 2; ++n)
#pragma unroll
      for (int kk = 0; kk < 2; ++kk) bA[n][kk] = RD_B(n, kk);
    __builtin_amdgcn_s_barrier();
    asm volatile("s_waitcnt lgkmcnt(0)" ::: "memory");
    __builtin_amdgcn_s_setprio(1);
#pragma unroll
    for (int m = 0; m < 4; ++m)
#pragma unroll
      for (int n = 0; n < 2; ++n)
#pragma unroll
        for (int kk = 0; kk < 2; ++kk)
          acc[m][n] = MFMA(afr[m][kk], bA[n][kk], acc[m][n]);
    __builtin_amdgcn_s_setprio(0);
    __builtin_amdgcn_s_barrier();

#pragma unroll
    for (int n = 0; n < 2; ++n)
#pragma unroll
      for (int kk = 0; kk < 2; ++kk) bB[n][kk] = RD_B(n + 2, kk);
    __builtin_amdgcn_s_barrier();
    asm volatile("s_waitcnt lgkmcnt(0)" ::: "memory");
    __builtin_amdgcn_s_setprio(1);
#pragma unroll
    for (int m = 0; m < 4; ++m)
#pragma unroll
      for (int n = 0; n < 2; ++n)
#pragma unroll
        for (int kk = 0; kk < 2; ++kk)
          acc[m][n + 2] = MFMA(afr[m][kk], bB[n][kk], acc[m][n + 2]);
    __builtin_amdgcn_s_setprio(0);
    __builtin_amdgcn_s_barrier();

#pragma unroll
    for (int m = 0; m < 4; ++m)
#pragma unroll
      for (int kk = 0; kk < 2; ++kk) afr[m][kk] = RD_A(m + 4, kk);
#pragma unroll
    for (int h = 0; h < 2; ++h)
#pragma unroll
      for (int i2 = 0; i2 < 2; ++i2) STAGE_B(h, i2, koff, aoff);
    __builtin_amdgcn_s_barrier();
    asm volatile("s_waitcnt lgkmcnt(0)" ::: "memory");
    __builtin_amdgcn_s_setprio(1);
#pragma unroll
    for (int m = 0; m < 4; ++m)
#pragma unroll
      for (int n = 0; n < 2; ++n)
#pragma unroll
        for (int kk = 0; kk < 2; ++kk)
          acc[m + 4][n + 2] = MFMA(afr[m][kk], bB[n][kk], acc[m + 4][n + 2]);
    __builtin_amdgcn_s_setprio(0);
    __builtin_amdgcn_s_barrier();

#pragma unroll
    for (int h = 0; h < 2; ++h)
#pragma unroll
      for (int i2 = 0; i2 < 2; ++i2) STAGE_A(h, i2, koff, aoff);
    __builtin_amdgcn_s_barrier();
    __builtin_amdgcn_s_setprio(1);
#pragma unroll
    for (int m = 0; m < 4; ++m)
#pragma unroll
      for (int n = 0; n < 2; ++n)
#pragma unroll
        for (int kk = 0; kk < 2; ++kk)
          acc[m + 4][n] = MFMA(afr[m][kk], bA[n][kk], acc[m + 4][n]);
    __builtin_amdgcn_s_setprio(0);
    asm volatile("s_waitcnt vmcnt(8)" ::: "memory");
    __builtin_amdgcn_s_barrier();
  }

  float bv[4];
#pragma unroll
  for (int n = 0; n < 4; ++n) bv[n] = bias[n0b + wc * 64 + n * 16 + li];
#pragma unroll
  for (int m = 0; m < 8; ++m) {
#pragma unroll
    for (int qi = 0; qi < 4; ++qi) {
      const int row = m0b + wr * 128 + m * 16 + ks * 4 + qi;
      float* orow = out + (size_t)row * 4096 + n0b + wc * 64 + li;
#pragma unroll
      for (int n = 0; n < 4; ++n) orow[n * 16] = acc[m][n][qi] + bv[n];
    }
  }
#undef STAGE_A
#undef STAGE_B
#undef RD_A
#undef RD_B
#undef MFMA
}

// ---------------------------------------------------------------------------
// ABLATION variants of the R2 structure. VAR bit0=MFMA, bit1=ds_read,
// bit2=stage. 2 reps of the 64-tile loop. Sink -> scratch (keeps work live).
// ---------------------------------------------------------------------------
template <int VAR>
__global__ __launch_bounds__(512, 2) void ablate(
    const unsigned short* __restrict__ A, const unsigned short* __restrict__ W,
    float4* __restrict__ snkbuf) {
  __shared__ __align__(1024) char lds[131072];

  const int tid  = threadIdx.x;
  const int lane = tid & 63;
  const int w    = tid >> 6;
  const int li   = lane & 15;
  const int ks   = lane >> 4;
  const int wr   = w >> 2;
  const int wc   = w & 3;
  const int LB   = (li * 64 + ks * 16) ^ (((li >> 3) & 1) << 5);

  const int bid = blockIdx.x;
  const int swz = (bid & 7) * 32 + (bid >> 3);
  const int m0b = (swz >> 4) * 256, n0b = (swz & 15) * 256;

  unsigned sA[2][2], sB[2][2];
#pragma unroll
  for (int i2 = 0; i2 < 2; ++i2) {
    int P = w * 2048 + i2 * 1024 + lane * 16;
    int L = P ^ (((P >> 9) & 1) << 5);
    int kk = L >> 13, row = (L >> 6) & 127, cb = L & 63;
#pragma unroll
    for (int h = 0; h < 2; ++h) {
      sA[h][i2] = (unsigned)((m0b + h * 128 + row) * 8192 + kk * 64 + cb);
      sB[h][i2] = (unsigned)((n0b + h * 128 + row) * 8192 + kk * 64 + cb);
    }
  }
  const char* Ac = (const char*)A;
  const char* Wc = (const char*)W;
  AS3 char* L3 = (AS3 char*)lds;

  const f32x4 vzero = {0.f, 0.f, 0.f, 0.f};
  f32x4 acc[8][4];
#pragma unroll
  for (int m = 0; m < 8; ++m)
#pragma unroll
    for (int n = 0; n < 4; ++n) acc[m][n] = vzero;

#define STAGE_A(h, i2, koffb, bufo) \
  __builtin_amdgcn_global_load_lds((AS1 unsigned int*)(Ac + sA[h][i2] + (koffb)), \
      (AS3 unsigned int*)(L3 + (bufo) + (h) * 16384 + w * 2048 + (i2) * 1024), 16, 0, 0)
#define STAGE_B(h, i2, koffb, bufo) \
  __builtin_amdgcn_global_load_lds((AS1 unsigned int*)(Wc + sB[h][i2] + (koffb)), \
      (AS3 unsigned int*)(L3 + 65536 + (bufo) + (h) * 16384 + w * 2048 + (i2) * 1024), 16, 0, 0)
#define RD_A(m, kk) (*(const bf16x8*)(lds + aoff + wr * 16384 + (kk) * 8192 + (m) * 1024 + LB))
#define RD_B(n, kk) (*(const bf16x8*)(lds + boff + (wc >> 1) * 16384 + (kk) * 8192 + \
                                      (wc & 1) * 4096 + (n) * 1024 + LB))
#define MFMA(a, b, c) __builtin_amdgcn_mfma_f32_16x16x32_bf16((a), (b), (c), 0, 0, 0)

  bf16x8 afr[4][2], bA[2][2], bB[2][2];
  {
    union { bf16x8 v; unsigned u[4]; } ci;
    ci.u[0] = ci.u[1] = ci.u[2] = ci.u[3] = 0x3f803f80u;
#pragma unroll
    for (int m = 0; m < 4; ++m)
#pragma unroll
      for (int kk = 0; kk < 2; ++kk) afr[m][kk] = ci.v;
#pragma unroll
    for (int n = 0; n < 2; ++n)
#pragma unroll
      for (int kk = 0; kk < 2; ++kk) { bA[n][kk] = ci.v; bB[n][kk] = ci.v; }
  }
  uint4 snk = {0u, 0u, 0u, 0u};

  if constexpr ((VAR & 4) != 0) {
#pragma unroll
    for (int tt = 0; tt < 2; ++tt) {
#pragma unroll
      for (int h = 0; h < 2; ++h)
#pragma unroll
        for (int i2 = 0; i2 < 2; ++i2) {
          STAGE_A(h, i2, tt * 128u, tt * 32768);
          STAGE_B(h, i2, tt * 128u, tt * 32768);
        }
    }
    asm volatile("s_waitcnt vmcnt(8)" ::: "memory");
  }
  __builtin_amdgcn_s_barrier();

  for (int r = 0; r < 2; ++r) {
    for (int t = 0; t < 64; ++t) {
      const int cur  = t & 1;
      const int aoff = cur * 32768;
      const int boff = 65536 + cur * 32768;
      const int ts   = (t + 2 < 64) ? t + 2 : 63;
      const unsigned koff = (unsigned)ts * 128u;

      // ---------- phase 1 ----------
      if constexpr ((VAR & 2) != 0) {
#pragma unroll
        for (int m = 0; m < 4; ++m)
#pragma unroll
          for (int kk = 0; kk < 2; ++kk) afr[m][kk] = RD_A(m, kk);
#pragma unroll
        for (int n = 0; n < 2; ++n)
#pragma unroll
          for (int kk = 0; kk < 2; ++kk) bA[n][kk] = RD_B(n, kk);
      }
      __builtin_amdgcn_s_barrier();
      if constexpr ((VAR & 2) != 0)
        asm volatile("s_waitcnt lgkmcnt(0)" ::: "memory");
      __builtin_amdgcn_s_setprio(1);
      if constexpr ((VAR & 1) != 0) {
#pragma unroll
        for (int m = 0; m < 4; ++m)
#pragma unroll
          for (int n = 0; n < 2; ++n)
#pragma unroll
            for (int kk = 0; kk < 2; ++kk)
              acc[m][n] = MFMA(afr[m][kk], bA[n][kk], acc[m][n]);
      } else if constexpr ((VAR & 2) != 0) {
#pragma unroll
        for (int m = 0; m < 4; ++m)
#pragma unroll
          for (int kk = 0; kk < 2; ++kk) sink16(snk, &afr[m][kk]);
#pragma unroll
        for (int n = 0; n < 2; ++n)
#pragma unroll
          for (int kk = 0; kk < 2; ++kk) sink16(snk, &bA[n][kk]);
      }
      __builtin_amdgcn_s_setprio(0);
      __builtin_amdgcn_s_barrier();

      // ---------- phase 2 ----------
      if constexpr ((VAR & 2) != 0) {
#pragma unroll
        for (int n = 0; n < 2; ++n)
#pragma unroll
          for (int kk = 0; kk < 2; ++kk) bB[n][kk] = RD_B(n + 2, kk);
      }
      __builtin_amdgcn_s_barrier();
      if constexpr ((VAR & 2) != 0)
        asm volatile("s_waitcnt lgkmcnt(0)" ::: "memory");
      __builtin_amdgcn_s_setprio(1);
      if constexpr ((VAR & 1) != 0) {
#pragma unroll
        for (int m = 0; m < 4; ++m)
#pragma unroll
          for (int n = 0; n < 2; ++n)
#pragma unroll
            for (int kk = 0; kk < 2; ++kk)
              acc[m][n + 2] = MFMA(afr[m][kk], bB[n][kk], acc[m][n + 2]);
      } else if constexpr ((VAR & 2) != 0) {
#pragma unroll
        for (int n = 0; n < 2; ++n)
#pragma unroll
          for (int kk = 0; kk < 2; ++kk) sink16(snk, &bB[n][kk]);
      }
      __builtin_amdgcn_s_setprio(0);
      __builtin_amdgcn_s_barrier();

      // ---------- phase 3 ----------
      if constexpr ((VAR & 2) != 0) {
#pragma unroll
        for (int m = 0; m < 4; ++m)
#pragma unroll
          for (int kk = 0; kk < 2; ++kk) afr[m][kk] = RD_A(m + 4, kk);
      }
      if constexpr ((VAR & 4) != 0) {
#pragma unroll
        for (int h = 0; h < 2; ++h)
#pragma unroll
          for (int i2 = 0; i2 < 2; ++i2) STAGE_B(h, i2, koff, aoff);
      }
      __builtin_amdgcn_s_barrier();
      if constexpr ((VAR & 2) != 0)
        asm volatile("s_waitcnt lgkmcnt(0)" ::: "memory");
      __builtin_amdgcn_s_setprio(1);
      if constexpr ((VAR & 1) != 0) {
#pragma unroll
        for (int m = 0; m < 4; ++m)
#pragma unroll
          for (int n = 0; n < 2; ++n)
#pragma unroll
            for (int kk = 0; kk < 2; ++kk)
              acc[m + 4][n + 2] = MFMA(afr[m][kk], bB[n][kk], acc[m + 4][n + 2]);
      } else if constexpr ((VAR & 2) != 0) {
#pragma unroll
        for (int m = 0; m < 4; ++m)
#pragma unroll
          for (int kk = 0; kk < 2; ++kk) sink16(snk, &afr[m][kk]);
      }
      __builtin_amdgcn_s_setprio(0);
      __builtin_amdgcn_s_barrier();

      // ---------- phase 4 ----------
      if constexpr ((VAR & 4) != 0) {
#pragma unroll
        for (int h = 0; h < 2; ++h)
#pragma unroll
          for (int i2 = 0; i2 < 2; ++i2) STAGE_A(h, i2, koff, aoff);
      }
      __builtin_amdgcn_s_barrier();
      __builtin_amdgcn_s_setprio(1);
      if constexpr ((VAR & 1) != 0) {
#pragma unroll
        for (int m = 0; m < 4; ++m)
#pragma unroll
          for (int n = 0; n < 2; ++n)
#pragma unroll
            for (int kk = 0; kk < 2; ++kk)
              acc[m + 4][n] = MFMA(afr[m][kk], bA[n][kk], acc[m + 4][n]);
      }
      __builtin_amdgcn_s_setprio(0);
      if constexpr ((VAR & 4) != 0)
        asm volatile("s_waitcnt vmcnt(8)" ::: "memory");
      __builtin_amdgcn_s_barrier();
    }
  }

  // sink: keep everything live
  f32x4 a = acc[0][0];
#pragma unroll
  for (int m = 0; m < 8; ++m)
#pragma unroll
    for (int n = 0; n < 4; ++n) {
      a[0] += acc[m][n][0]; a[1] += acc[m][n][1];
      a[2] += acc[m][n][2]; a[3] += acc[m][n][3];
    }
  float4 o;
  o.x = a[0] + __builtin_bit_cast(float, snk.x);
  o.y = a[1] + __builtin_bit_cast(float, snk.y);
  o.z = a[2] + __builtin_bit_cast(float, snk.z);
  o.w = a[3] + __builtin_bit_cast(float, snk.w);
  snkbuf[bid * 512 + tid] = o;
#undef STAGE_A
#undef STAGE_B
#undef RD_A
#undef RD_B
#undef MFMA
}

// ---------------------------------------------------------------------------
extern "C" void kernel_launch(void* const* d_in, const int* in_sizes, int n_in,
                              void* d_out, int out_size, void* d_ws, size_t ws_size,
                              hipStream_t stream) {
  const float* q = (const float*)d_in[0];
  const float* k = (const float*)d_in[1];
  const float* v = (const float*)d_in[2];
  const float* w = (const float*)d_in[3];
  const float* b = (const float*)d_in[4];
  float* out = (float*)d_out;
  char* ws = (char*)d_ws;

  unsigned short* attn = (unsigned short*)ws;                      // 32 MB
  unsigned short* KT2  = (unsigned short*)(ws + (size_t)33554432); // 32 MB
  unsigned short* VT2  = (unsigned short*)(ws + (size_t)67108864); // 32 MB
  unsigned short* wbf  = KT2;  // reuse KT2 region after attention
  float4* snkbuf = (float4*)(ws + (size_t)67108864);  // VT2 region, dead after attn

  kv_transpose<<<dim3(2048, 2), 256, 0, stream>>>(k, v, KT2, VT2);
  attn_kernel<<<1024, 256, 0, stream>>>(q, KT2, VT2, attn);
  convw<<<8192, 256, 0, stream>>>(w, wbf);

  // ---- diagnostic ablation (results via rocprof per-dispatch dur_us) ----
  ablate<1><<<256, 512, 0, stream>>>(attn, wbf, snkbuf);  // MFMA+barriers only
  ablate<2><<<256, 512, 0, stream>>>(attn, wbf, snkbuf);  // ds_read+barriers only
  ablate<3><<<256, 512, 0, stream>>>(attn, wbf, snkbuf);  // MFMA+ds_read, no stage

  proj_gemm8<<<256, 512, 0, stream>>>(attn, wbf, b, out);
}

// Round 7
// 236.171 us; speedup vs baseline: 2.5525x; 2.5525x over previous
//
#include <hip/hip_runtime.h>

#define AS1 __attribute__((address_space(1)))
#define AS3 __attribute__((address_space(3)))

typedef __bf16 bf16x8 __attribute__((ext_vector_type(8)));
typedef float f32x4 __attribute__((ext_vector_type(4)));

__device__ __forceinline__ unsigned short f2bf(float f) {
  unsigned int u = __builtin_bit_cast(unsigned int, f);
  u += 0x7fffu + ((u >> 16) & 1u);   // round-to-nearest-even
  return (unsigned short)(u >> 16);
}

// ---------------------------------------------------------------------------
// Transpose K/V (f32, [b,t,h*256+j]) -> bf16 tiles [pp][s][j:256][t:32]
// ---------------------------------------------------------------------------
__global__ __launch_bounds__(256) void kv_transpose(
    const float* __restrict__ key, const float* __restrict__ value,
    unsigned short* __restrict__ KT2, unsigned short* __restrict__ VT2) {
  __shared__ float tr[32 * 33];
  const int tid = threadIdx.x;
  const int ts  = blockIdx.y;          // 0 = K, 1 = V
  const int pp  = blockIdx.x >> 3;
  const int s   = blockIdx.x & 7;
  const int b   = ts ? (pp >> 4) : (pp & 15);
  const int h   = ts ? (pp & 15) : (pp >> 4);
  const float* src = (ts ? value : key) + ((size_t)(b * 256 + s * 32)) * 4096 + h * 256;
  unsigned short* dst = (ts ? VT2 : KT2) + (size_t)(pp * 8 + s) * 8192;
  const int tt = tid >> 3;   // 0..31
  const int q8 = tid & 7;    // 0..7
  for (int jb = 0; jb < 8; ++jb) {
    float4 v = *(const float4*)(src + (size_t)tt * 4096 + jb * 32 + q8 * 4);
    tr[tt * 33 + q8 * 4 + 0] = v.x;
    tr[tt * 33 + q8 * 4 + 1] = v.y;
    tr[tt * 33 + q8 * 4 + 2] = v.z;
    tr[tt * 33 + q8 * 4 + 3] = v.w;
    __syncthreads();
    ushort4 o;
    o.x = f2bf(tr[(q8 * 4 + 0) * 33 + tt]);
    o.y = f2bf(tr[(q8 * 4 + 1) * 33 + tt]);
    o.z = f2bf(tr[(q8 * 4 + 2) * 33 + tt]);
    o.w = f2bf(tr[(q8 * 4 + 3) * 33 + tt]);
    *(ushort4*)(dst + (jb * 32 + tt) * 32 + q8 * 4) = o;
    __syncthreads();
  }
}

// ---------------------------------------------------------------------------
// Attention (validated).
// ---------------------------------------------------------------------------
__global__ __launch_bounds__(256, 2) void attn_kernel(
    const float* __restrict__ qin, const unsigned short* __restrict__ KT2,
    const unsigned short* __restrict__ VT2, unsigned short* __restrict__ attn) {
  __shared__ __align__(16) unsigned short kv[8192];
  __shared__ __align__(16) unsigned short plds[4 * 16 * 264];

  const int tid  = threadIdx.x;
  const int lane = tid & 63;
  const int wave = tid >> 6;
  const int li   = lane & 15;
  const int ks   = lane >> 4;

  const int bid = blockIdx.x;
  const int pp  = (bid & 7) * 32 + ((bid >> 3) & 31);
  const int ib  = bid >> 8;
  const int x = pp >> 4, y = pp & 15;
  const int i0 = ib * 64 + wave * 16;

  bf16x8 qf[8];
  {
    const float* qrow = qin + ((size_t)(y * 256 + i0 + li)) * 4096 + x * 256 + ks * 8;
#pragma unroll
    for (int s = 0; s < 8; ++s) {
      float4 v0 = *(const float4*)(qrow + s * 32);
      float4 v1 = *(const float4*)(qrow + s * 32 + 4);
      union { bf16x8 v; unsigned short u[8]; } t;
      t.u[0] = f2bf(v0.x * 0.0625f); t.u[1] = f2bf(v0.y * 0.0625f);
      t.u[2] = f2bf(v0.z * 0.0625f); t.u[3] = f2bf(v0.w * 0.0625f);
      t.u[4] = f2bf(v1.x * 0.0625f); t.u[5] = f2bf(v1.y * 0.0625f);
      t.u[6] = f2bf(v1.z * 0.0625f); t.u[7] = f2bf(v1.w * 0.0625f);
      qf[s] = t.v;
    }
  }

  const f32x4 vzero = {0.f, 0.f, 0.f, 0.f};
  f32x4 sacc[16];
#pragma unroll
  for (int f = 0; f < 16; ++f) sacc[f] = vzero;

  const unsigned short* ktile = KT2 + (size_t)pp * 65536;
#pragma unroll
  for (int s = 0; s < 8; ++s) {
    __syncthreads();
#pragma unroll
    for (int cc = 0; cc < 4; ++cc) {
      const unsigned short* g = ktile + (size_t)s * 8192 + (cc * 256 + tid) * 8;
      __builtin_amdgcn_global_load_lds((AS1 unsigned int*)g,
          (AS3 unsigned int*)((AS3 char*)kv + cc * 4096 + wave * 1024), 16, 0, 0);
    }
    __syncthreads();
#pragma unroll
    for (int f = 0; f < 16; ++f) {
      bf16x8 bfr = *(const bf16x8*)&kv[(f * 16 + li) * 32 + ks * 8];
      sacc[f] = __builtin_amdgcn_mfma_f32_16x16x32_bf16(qf[s], bfr, sacc[f], 0, 0, 0);
    }
  }

  float sm[4];
#pragma unroll
  for (int qi = 0; qi < 4; ++qi) {
    float m = sacc[0][qi];
#pragma unroll
    for (int f = 1; f < 16; ++f) m = fmaxf(m, sacc[f][qi]);
    m = fmaxf(m, __shfl_xor(m, 1));
    m = fmaxf(m, __shfl_xor(m, 2));
    m = fmaxf(m, __shfl_xor(m, 4));
    m = fmaxf(m, __shfl_xor(m, 8));
    float ssum = 0.f;
#pragma unroll
    for (int f = 0; f < 16; ++f) {
      float pv = __expf(sacc[f][qi] - m);
      sacc[f][qi] = pv;
      ssum += pv;
    }
    ssum += __shfl_xor(ssum, 1);
    ssum += __shfl_xor(ssum, 2);
    ssum += __shfl_xor(ssum, 4);
    ssum += __shfl_xor(ssum, 8);
    sm[qi] = ssum;
  }

  unsigned short* pw = plds + wave * 4224;
#pragma unroll
  for (int f = 0; f < 16; ++f)
#pragma unroll
    for (int qi = 0; qi < 4; ++qi)
      pw[(ks * 4 + qi) * 264 + f * 16 + li] = f2bf(sacc[f][qi]);

  f32x4 oacc[16];
#pragma unroll
  for (int f = 0; f < 16; ++f) oacc[f] = vzero;
  const unsigned short* vtile = VT2 + (size_t)pp * 65536;
  const unsigned short* pr = plds + wave * 4224 + li * 264;
#pragma unroll
  for (int s2 = 0; s2 < 8; ++s2) {
    __syncthreads();
#pragma unroll
    for (int cc = 0; cc < 4; ++cc) {
      const unsigned short* g = vtile + (size_t)s2 * 8192 + (cc * 256 + tid) * 8;
      __builtin_amdgcn_global_load_lds((AS1 unsigned int*)g,
          (AS3 unsigned int*)((AS3 char*)kv + cc * 4096 + wave * 1024), 16, 0, 0);
    }
    __syncthreads();
    bf16x8 afr = *(const bf16x8*)&pr[s2 * 32 + ks * 8];
#pragma unroll
    for (int f = 0; f < 16; ++f) {
      bf16x8 bfr = *(const bf16x8*)&kv[(f * 16 + li) * 32 + ks * 8];
      oacc[f] = __builtin_amdgcn_mfma_f32_16x16x32_bf16(afr, bfr, oacc[f], 0, 0, 0);
    }
  }

  float rs4[4];
#pragma unroll
  for (int qi = 0; qi < 4; ++qi) rs4[qi] = 1.0f / sm[qi];
  unsigned short* abase = attn + (size_t)(x * 256 + i0 + ks * 4) * 4096 + y * 256 + li;
#pragma unroll
  for (int f = 0; f < 16; ++f)
#pragma unroll
    for (int qi = 0; qi < 4; ++qi)
      abase[(size_t)qi * 4096 + f * 16] = f2bf(oacc[f][qi] * rs4[qi]);
}

// ---------------------------------------------------------------------------
// out_w f32 -> bf16
// ---------------------------------------------------------------------------
__global__ __launch_bounds__(256) void convw(const float* __restrict__ w,
                                             unsigned short* __restrict__ o) {
  const int i = blockIdx.x * 256 + threadIdx.x;
  const float4* s = (const float4*)w + (size_t)i * 2;
  float4 v0 = s[0], v1 = s[1];
  uint4 pk;
  pk.x = (unsigned)f2bf(v0.x) | ((unsigned)f2bf(v0.y) << 16);
  pk.y = (unsigned)f2bf(v0.z) | ((unsigned)f2bf(v0.w) << 16);
  pk.z = (unsigned)f2bf(v1.x) | ((unsigned)f2bf(v1.y) << 16);
  pk.w = (unsigned)f2bf(v1.z) | ((unsigned)f2bf(v1.w) << 16);
  *((uint4*)o + i) = pk;
}

// ---------------------------------------------------------------------------
// 256x256xBK=32 GEMM, ring-4 LDS slots, ONE barrier per K-tile.
// Evidence (R6 ablation): MFMA+barrier floor 3590 cyc/tile@BK64 (8 bars) vs
// 2484 pipe floor -> each phase costs ~276 cyc refill; ds_reads fully hide
// under MFMA via cross-wave slip. So: minimize phases. Per tile:
//   {12 ds_reads(slot t&3); stage 4 loads -> slot (t+3)&3; lgkm0;
//    setprio1; 32 MFMA; setprio0; vmcnt(8); barrier}
// Ring-4 safety: slot s rewritten at t+1 targets slot read at t; every
// wave's lgkm0 precedes t's end-barrier -> reads drained. vmcnt(8) drains
// the 2-tile-old stage batch -> slot t+1 certified at the barrier.
// ---------------------------------------------------------------------------
__global__ __launch_bounds__(512, 2) void proj_gemm8(
    const unsigned short* __restrict__ A, const unsigned short* __restrict__ W,
    const float* __restrict__ bias, float* __restrict__ out) {
  __shared__ __align__(1024) char lds[131072];   // 4 slots x (A 16K | B 16K)

  const int tid  = threadIdx.x;
  const int lane = tid & 63;
  const int w    = tid >> 6;
  const int li   = lane & 15;
  const int ks   = lane >> 4;
  const int wr   = w >> 2;          // 0..1 (M half)
  const int wc   = w & 3;           // 0..3 (N quarter)
  // proven-0-conflict read base (R2): 64B rows, XOR row-bit3 into bank bit5
  const int LB   = (li * 64 + ks * 16) ^ (((li >> 3) & 1) << 5);

  const int bid = blockIdx.x;
  const int swz = (bid & 7) * 32 + (bid >> 3);      // XCD swizzle, 256 % 8 == 0
  const int m0b = (swz >> 4) * 256, n0b = (swz & 15) * 256;

  // staging: thread covers physical bytes {tid*16, 8192+tid*16} of a 16KB region
  unsigned sA[2], sB[2];
  int dstP[2];
#pragma unroll
  for (int j = 0; j < 2; ++j) {
    int P = j * 8192 + tid * 16;
    int L = P ^ (((P >> 9) & 1) << 5);              // involution (row bit3 <-> bank)
    int row = L >> 6, col = L & 63;                 // row 0..255, col 0..63 bytes
    dstP[j] = P;
    sA[j] = (unsigned)((m0b + row) * 8192 + col);
    sB[j] = (unsigned)((n0b + row) * 8192 + col);
  }
  const char* Ac = (const char*)A;
  const char* Wc = (const char*)W;
  AS3 char* L3 = (AS3 char*)lds;

  const f32x4 vzero = {0.f, 0.f, 0.f, 0.f};
  f32x4 acc[8][4];
#pragma unroll
  for (int m = 0; m < 8; ++m)
#pragma unroll
    for (int n = 0; n < 4; ++n) acc[m][n] = vzero;

#define STAGE(kt, slot) do {                                                   \
    const unsigned _ko = (unsigned)(kt) * 64u;                                 \
    const int _sl = (slot) * 32768;                                            \
    _Pragma("unroll") for (int j = 0; j < 2; ++j) {                            \
      __builtin_amdgcn_global_load_lds((AS1 unsigned int*)(Ac + sA[j] + _ko),  \
          (AS3 unsigned int*)(L3 + _sl + dstP[j]), 16, 0, 0);                  \
      __builtin_amdgcn_global_load_lds((AS1 unsigned int*)(Wc + sB[j] + _ko),  \
          (AS3 unsigned int*)(L3 + _sl + 16384 + dstP[j]), 16, 0, 0);          \
    } } while (0)
#define RD_A(S, M) (*(const bf16x8*)(lds + (S) + wr * 8192 + (M) * 1024 + LB))
#define RD_B(S, N) (*(const bf16x8*)(lds + (S) + 16384 + wc * 4096 + (N) * 1024 + LB))
#define MFMA(a, b, c) __builtin_amdgcn_mfma_f32_16x16x32_bf16((a), (b), (c), 0, 0, 0)

  // ---- prologue: stage tiles 0,1,2 into slots 0,1,2 ----
  STAGE(0, 0); STAGE(1, 1); STAGE(2, 2);
  asm volatile("s_waitcnt vmcnt(8)" ::: "memory");  // slot 0 complete
  __builtin_amdgcn_s_barrier();

  for (int t = 0; t < 128; ++t) {
    const int sl = (t & 3) * 32768;
    bf16x8 af[8], bf[4];
#pragma unroll
    for (int m = 0; m < 8; ++m) af[m] = RD_A(sl, m);
#pragma unroll
    for (int n = 0; n < 4; ++n) bf[n] = RD_B(sl, n);

    const int kt = (t + 3 < 128) ? t + 3 : 127;     // clamped tail: dead slots
    STAGE(kt, (t + 3) & 3);

    asm volatile("s_waitcnt lgkmcnt(0)" ::: "memory");
    __builtin_amdgcn_s_setprio(1);
#pragma unroll
    for (int m = 0; m < 8; ++m)
#pragma unroll
      for (int n = 0; n < 4; ++n)
        acc[m][n] = MFMA(af[m], bf[n], acc[m][n]);
    __builtin_amdgcn_s_setprio(0);

    asm volatile("s_waitcnt vmcnt(8)" ::: "memory");  // slot t+1 certified
    __builtin_amdgcn_s_barrier();
  }

  // ---- epilogue ----
  float bv[4];
#pragma unroll
  for (int n = 0; n < 4; ++n) bv[n] = bias[n0b + wc * 64 + n * 16 + li];
#pragma unroll
  for (int m = 0; m < 8; ++m) {
#pragma unroll
    for (int qi = 0; qi < 4; ++qi) {
      const int row = m0b + wr * 128 + m * 16 + ks * 4 + qi;
      float* orow = out + (size_t)row * 4096 + n0b + wc * 64 + li;
#pragma unroll
      for (int n = 0; n < 4; ++n) orow[n * 16] = acc[m][n][qi] + bv[n];
    }
  }
#undef STAGE
#undef RD_A
#undef RD_B
#undef MFMA
}

// ---------------------------------------------------------------------------
extern "C" void kernel_launch(void* const* d_in, const int* in_sizes, int n_in,
                              void* d_out, int out_size, void* d_ws, size_t ws_size,
                              hipStream_t stream) {
  const float* q = (const float*)d_in[0];
  const float* k = (const float*)d_in[1];
  const float* v = (const float*)d_in[2];
  const float* w = (const float*)d_in[3];
  const float* b = (const float*)d_in[4];
  float* out = (float*)d_out;
  char* ws = (char*)d_ws;

  unsigned short* attn = (unsigned short*)ws;                      // 32 MB
  unsigned short* KT2  = (unsigned short*)(ws + (size_t)33554432); // 32 MB
  unsigned short* VT2  = (unsigned short*)(ws + (size_t)67108864); // 32 MB
  unsigned short* wbf  = KT2;  // reuse KT2 region after attention is done

  kv_transpose<<<dim3(2048, 2), 256, 0, stream>>>(k, v, KT2, VT2);
  attn_kernel<<<1024, 256, 0, stream>>>(q, KT2, VT2, attn);
  convw<<<8192, 256, 0, stream>>>(w, wbf);
  proj_gemm8<<<256, 512, 0, stream>>>(attn, wbf, b, out);
}